// Round 1
// baseline (525.968 us; speedup 1.0000x reference)
//
#include <hip/hip_runtime.h>
#include <hip/hip_bf16.h>
#include <stdint.h>

#define NN 100000
#define NE 1600000
#define HD 128
#define NG 500
#define NPG 200

// ---------- edge dtype helper (int32 vs int64 detected at runtime) ----------
__device__ __forceinline__ int edge_at(const void* p, int is64, int idx) {
  return is64 ? (int)((const long long*)p)[idx] : ((const int*)p)[idx];
}

__global__ void k_detect(const void* __restrict__ edges, int* __restrict__ flag) {
  if (threadIdx.x == 0 && blockIdx.x == 0) {
    const unsigned int* p = (const unsigned int*)edges;
    unsigned int odd = 0u, even = 0u;
    for (int i = 0; i < 256; ++i) { even |= p[2 * i]; odd |= p[2 * i + 1]; }
    flag[0] = (odd == 0u && even != 0u) ? 1 : 0;  // all-odd-zero => int64
  }
}

// ---------- degree count ----------
__global__ void k_count(const void* __restrict__ edges, const int* __restrict__ flag,
                        int* __restrict__ cnt) {
  int e = blockIdx.x * blockDim.x + threadIdx.x;
  if (e >= NE) return;
  int f = flag[0];
  int d = edge_at(edges, f, NE + e);
  atomicAdd(&cnt[d], 1);
}

__global__ void k_dinv(const int* __restrict__ cnt, float* __restrict__ dinv) {
  int i = blockIdx.x * blockDim.x + threadIdx.x;
  if (i < NN) dinv[i] = rsqrtf((float)(cnt[i] + 1));  // +1 self loop
}

// ---------- exclusive scan of cnt -> rowstart (3 kernels) ----------
__global__ void k_scan_block(const int* __restrict__ cnt, int* __restrict__ rowstart,
                             int* __restrict__ bsums) {
  __shared__ int s[256];
  int tid = threadIdx.x;
  int i = blockIdx.x * 256 + tid;
  int v = (i < NN) ? cnt[i] : 0;
  s[tid] = v;
  __syncthreads();
  for (int off = 1; off < 256; off <<= 1) {
    int t = (tid >= off) ? s[tid - off] : 0;
    __syncthreads();
    s[tid] += t;
    __syncthreads();
  }
  if (i < NN) rowstart[i] = s[tid] - v;          // exclusive
  if (tid == 255) bsums[blockIdx.x] = s[255];     // block total
}

__global__ void k_scan_sums(int* __restrict__ bsums, int nb) {
  __shared__ int s[512];
  int tid = threadIdx.x;
  int v = (tid < nb) ? bsums[tid] : 0;
  s[tid] = v;
  __syncthreads();
  for (int off = 1; off < 512; off <<= 1) {
    int t = (tid >= off) ? s[tid - off] : 0;
    __syncthreads();
    s[tid] += t;
    __syncthreads();
  }
  if (tid < nb) bsums[tid] = s[tid] - v;          // exclusive
}

__global__ void k_scan_add(int* __restrict__ rowstart, const int* __restrict__ bsums) {
  int i = blockIdx.x * blockDim.x + threadIdx.x;
  if (i < NN) rowstart[i] += bsums[i >> 8];
  if (i == 0) rowstart[NN] = NE;
}

// ---------- CSR fill: (src, norm) per edge ----------
__global__ void k_fill(const void* __restrict__ edges, const int* __restrict__ flag,
                       const int* __restrict__ rowstart, int* __restrict__ fillc,
                       const float* __restrict__ dinv, int2* __restrict__ csr) {
  int e = blockIdx.x * blockDim.x + threadIdx.x;
  if (e >= NE) return;
  int f = flag[0];
  int s = edge_at(edges, f, e);
  int d = edge_at(edges, f, NE + e);
  int pos = atomicAdd(&fillc[d], 1);
  int2 v;
  v.x = s;
  v.y = __float_as_int(dinv[s] * dinv[d]);
  csr[rowstart[d] + pos] = v;
}

// ---------- aggregation: out[v] = dinv[v]^2 * in[v] + sum_e norm * in[src] ----------
__global__ __launch_bounds__(256) void k_agg(const float* __restrict__ in,
                                             float* __restrict__ out,
                                             const int* __restrict__ rowstart,
                                             const int2* __restrict__ csr,
                                             const float* __restrict__ dinv) {
  int g = blockIdx.x * 8 + (threadIdx.x >> 5);  // node (half-wave per node)
  if (g >= NN) return;
  int lane = threadIdx.x & 31;
  const float4* in4 = (const float4*)in;

  float dv = dinv[g];
  float s0 = dv * dv;
  float4 xv = in4[(size_t)g * 32 + lane];
  float4 acc;
  acc.x = s0 * xv.x; acc.y = s0 * xv.y; acc.z = s0 * xv.z; acc.w = s0 * xv.w;

  int i = rowstart[g], end = rowstart[g + 1];
  for (; i + 1 < end; i += 2) {
    int2 e0 = csr[i], e1 = csr[i + 1];
    float n0 = __int_as_float(e0.y), n1 = __int_as_float(e1.y);
    float4 v0 = in4[(size_t)e0.x * 32 + lane];
    float4 v1 = in4[(size_t)e1.x * 32 + lane];
    acc.x = fmaf(n0, v0.x, acc.x); acc.y = fmaf(n0, v0.y, acc.y);
    acc.z = fmaf(n0, v0.z, acc.z); acc.w = fmaf(n0, v0.w, acc.w);
    acc.x = fmaf(n1, v1.x, acc.x); acc.y = fmaf(n1, v1.y, acc.y);
    acc.z = fmaf(n1, v1.z, acc.z); acc.w = fmaf(n1, v1.w, acc.w);
  }
  if (i < end) {
    int2 e0 = csr[i];
    float n0 = __int_as_float(e0.y);
    float4 v0 = in4[(size_t)e0.x * 32 + lane];
    acc.x = fmaf(n0, v0.x, acc.x); acc.y = fmaf(n0, v0.y, acc.y);
    acc.z = fmaf(n0, v0.z, acc.z); acc.w = fmaf(n0, v0.w, acc.w);
  }
  ((float4*)out)[(size_t)g * 32 + lane] = acc;
}

// ---------- fp32 GEMM: out[M x 128] = A[M x 128] @ W[128 x 128] + bias (opt relu) ----------
__global__ __launch_bounds__(256) void k_gemm(const float* __restrict__ A,
                                              const float* __restrict__ W,
                                              const float* __restrict__ bias,
                                              float* __restrict__ out, int M, int relu) {
  __shared__ float Xs[32 * 132];  // [k][row], row stride 132 (conflict-free b128 reads)
  __shared__ float Ws[32 * 128];  // [k][c]
  const int tid = threadIdx.x;
  const int row0 = blockIdx.x * 128;
  const int rg = tid >> 4, cg = tid & 15;
  const int r0 = rg * 8, c0 = cg * 8;

  float bl[8];
#pragma unroll
  for (int j = 0; j < 8; ++j) bl[j] = bias[c0 + j];

  float acc[8][8];
#pragma unroll
  for (int i = 0; i < 8; ++i)
#pragma unroll
    for (int j = 0; j < 8; ++j) acc[i][j] = 0.f;

  for (int kt = 0; kt < 128; kt += 32) {
    __syncthreads();
    // stage X^T (128 rows x 32 k)
#pragma unroll
    for (int i = tid; i < 1024; i += 256) {
      int r = i >> 3, c4 = i & 7;
      float4 v = make_float4(0.f, 0.f, 0.f, 0.f);
      if (row0 + r < M) v = *(const float4*)&A[(size_t)(row0 + r) * 128 + kt + c4 * 4];
      Xs[(c4 * 4 + 0) * 132 + r] = v.x;
      Xs[(c4 * 4 + 1) * 132 + r] = v.y;
      Xs[(c4 * 4 + 2) * 132 + r] = v.z;
      Xs[(c4 * 4 + 3) * 132 + r] = v.w;
    }
    // stage W (32 k x 128 c)
#pragma unroll
    for (int i = tid; i < 1024; i += 256) {
      int k = i >> 5, c4 = i & 31;
      *(float4*)&Ws[k * 128 + c4 * 4] = *(const float4*)&W[(size_t)(kt + k) * 128 + c4 * 4];
    }
    __syncthreads();
#pragma unroll 8
    for (int k = 0; k < 32; ++k) {
      float4 x0 = *(const float4*)&Xs[k * 132 + r0];
      float4 x1 = *(const float4*)&Xs[k * 132 + r0 + 4];
      float4 w0 = *(const float4*)&Ws[k * 128 + c0];
      float4 w1 = *(const float4*)&Ws[k * 128 + c0 + 4];
      float xr[8] = {x0.x, x0.y, x0.z, x0.w, x1.x, x1.y, x1.z, x1.w};
      float wr[8] = {w0.x, w0.y, w0.z, w0.w, w1.x, w1.y, w1.z, w1.w};
#pragma unroll
      for (int i = 0; i < 8; ++i)
#pragma unroll
        for (int j = 0; j < 8; ++j) acc[i][j] = fmaf(xr[i], wr[j], acc[i][j]);
    }
  }

#pragma unroll
  for (int i = 0; i < 8; ++i) {
    int r = row0 + r0 + i;
    if (r < M) {
      float o[8];
#pragma unroll
      for (int j = 0; j < 8; ++j) {
        float v = acc[i][j] + bl[j];
        if (relu) v = fmaxf(v, 0.f);
        o[j] = v;
      }
      *(float4*)&out[(size_t)r * 128 + c0] = make_float4(o[0], o[1], o[2], o[3]);
      *(float4*)&out[(size_t)r * 128 + c0 + 4] = make_float4(o[4], o[5], o[6], o[7]);
    }
  }
}

// ---------- per-graph mean pool (contiguous 200-node segments) ----------
__global__ void k_pool(const float* __restrict__ in, float* __restrict__ outp) {
  int g = blockIdx.x, c = threadIdx.x;
  float s = 0.f;
  for (int v = 0; v < NPG; ++v) s += in[((size_t)g * NPG + v) * HD + c];
  outp[g * HD + c] = s / (float)NPG;
}

extern "C" void kernel_launch(void* const* d_in, const int* in_sizes, int n_in,
                              void* d_out, int out_size, void* d_ws, size_t ws_size,
                              hipStream_t stream) {
  const float* x  = (const float*)d_in[0];
  const void* edges = d_in[1];
  const float* W1 = (const float*)d_in[3];
  const float* b1 = (const float*)d_in[4];
  const float* W2 = (const float*)d_in[5];
  const float* b2 = (const float*)d_in[6];
  float* out = (float*)d_out;

  // workspace layout (bytes), ~117.1 MB total
  char* ws = (char*)d_ws;
  int*   cnt      = (int*)(ws + 0);          // 400000
  int*   fillc    = (int*)(ws + 400000);     // 400000 (zeroed together with cnt)
  int*   rowstart = (int*)(ws + 800000);     // 400016
  int*   bsums    = (int*)(ws + 1200016);    // 2048
  float* dinv     = (float*)(ws + 1202064);  // 400000
  int*   flag     = (int*)(ws + 1602064);    // 16
  int2*  csr      = (int2*)(ws + 1602080);   // 12.8 MB
  float* agg      = (float*)(ws + 14402080); // 51.2 MB
  float* h1       = (float*)(ws + 65602080); // 51.2 MB
  float* pool     = (float*)(ws + 116802080);// 256 KB

  hipMemsetAsync(cnt, 0, 800000, stream);  // cnt + fillc

  k_detect<<<1, 64, 0, stream>>>(edges, flag);
  k_count<<<(NE + 255) / 256, 256, 0, stream>>>(edges, flag, cnt);
  k_dinv<<<(NN + 255) / 256, 256, 0, stream>>>(cnt, dinv);
  k_scan_block<<<391, 256, 0, stream>>>(cnt, rowstart, bsums);
  k_scan_sums<<<1, 512, 0, stream>>>(bsums, 391);
  k_scan_add<<<391, 256, 0, stream>>>(rowstart, bsums);
  k_fill<<<(NE + 255) / 256, 256, 0, stream>>>(edges, flag, rowstart, fillc, dinv, csr);

  // conv1: agg = Agg(x); h1 = relu(agg @ W1 + b1)
  k_agg<<<NN / 8, 256, 0, stream>>>(x, agg, rowstart, csr, dinv);
  k_gemm<<<(NN + 127) / 128, 256, 0, stream>>>(agg, W1, b1, h1, NN, 1);
  // conv2 (pool-before-GEMM): agg = Agg(h1); pool = mean_g(agg); out = pool @ W2 + b2
  k_agg<<<NN / 8, 256, 0, stream>>>(h1, agg, rowstart, csr, dinv);
  k_pool<<<NG, 128, 0, stream>>>(agg, pool);
  k_gemm<<<(NG + 127) / 128, 256, 0, stream>>>(pool, W2, b2, out, NG, 0);
}

// Round 2
// 410.407 us; speedup vs baseline: 1.2816x; 1.2816x over previous
//
#include <hip/hip_runtime.h>
#include <hip/hip_bf16.h>
#include <stdint.h>

#define NN 100000
#define NE 1600000
#define HD 128
#define NG 500
#define NPG 200

// ---------- bf16 helpers (bit-level, RNE) ----------
__device__ __forceinline__ float bflo(unsigned int u) { return __uint_as_float(u << 16); }
__device__ __forceinline__ float bfhi(unsigned int u) { return __uint_as_float(u & 0xffff0000u); }
__device__ __forceinline__ unsigned int packbf(float a, float b) {
  unsigned int ua = __float_as_uint(a), ub = __float_as_uint(b);
  ua += 0x7fffu + ((ua >> 16) & 1u);
  ub += 0x7fffu + ((ub >> 16) & 1u);
  return (ua >> 16) | (ub & 0xffff0000u);
}

// ---------- edge dtype helper (int32 vs int64 detected at runtime) ----------
__device__ __forceinline__ int edge_at(const void* p, int is64, int idx) {
  return is64 ? (int)((const long long*)p)[idx] : ((const int*)p)[idx];
}

__global__ void k_detect(const void* __restrict__ edges, int* __restrict__ flag) {
  if (threadIdx.x == 0 && blockIdx.x == 0) {
    const unsigned int* p = (const unsigned int*)edges;
    unsigned int odd = 0u, even = 0u;
    for (int i = 0; i < 256; ++i) { even |= p[2 * i]; odd |= p[2 * i + 1]; }
    flag[0] = (odd == 0u && even != 0u) ? 1 : 0;  // all-odd-zero => int64
  }
}

// ---------- degree count ----------
__global__ void k_count(const void* __restrict__ edges, const int* __restrict__ flag,
                        int* __restrict__ cnt) {
  int e = blockIdx.x * blockDim.x + threadIdx.x;
  if (e >= NE) return;
  int f = flag[0];
  int d = edge_at(edges, f, NE + e);
  atomicAdd(&cnt[d], 1);
}

__global__ void k_dinv(const int* __restrict__ cnt, float* __restrict__ dinv) {
  int i = blockIdx.x * blockDim.x + threadIdx.x;
  if (i < NN) dinv[i] = rsqrtf((float)(cnt[i] + 1));  // +1 self loop
}

// ---------- exclusive scan of cnt -> rowstart ----------
__global__ void k_scan_block(const int* __restrict__ cnt, int* __restrict__ rowstart,
                             int* __restrict__ bsums) {
  __shared__ int s[256];
  int tid = threadIdx.x;
  int i = blockIdx.x * 256 + tid;
  int v = (i < NN) ? cnt[i] : 0;
  s[tid] = v;
  __syncthreads();
  for (int off = 1; off < 256; off <<= 1) {
    int t = (tid >= off) ? s[tid - off] : 0;
    __syncthreads();
    s[tid] += t;
    __syncthreads();
  }
  if (i < NN) rowstart[i] = s[tid] - v;
  if (tid == 255) bsums[blockIdx.x] = s[255];
}

__global__ void k_scan_sums(int* __restrict__ bsums, int nb) {
  __shared__ int s[512];
  int tid = threadIdx.x;
  int v = (tid < nb) ? bsums[tid] : 0;
  s[tid] = v;
  __syncthreads();
  for (int off = 1; off < 512; off <<= 1) {
    int t = (tid >= off) ? s[tid - off] : 0;
    __syncthreads();
    s[tid] += t;
    __syncthreads();
  }
  if (tid < nb) bsums[tid] = s[tid] - v;
}

__global__ void k_scan_add(int* __restrict__ rowstart, const int* __restrict__ bsums) {
  int i = blockIdx.x * blockDim.x + threadIdx.x;
  if (i < NN) rowstart[i] += bsums[i >> 8];
  if (i == 0) rowstart[NN] = NE;
}

// ---------- CSR fill: (src, norm) per edge ----------
__global__ void k_fill(const void* __restrict__ edges, const int* __restrict__ flag,
                       const int* __restrict__ rowstart, int* __restrict__ fillc,
                       const float* __restrict__ dinv, int2* __restrict__ csr) {
  int e = blockIdx.x * blockDim.x + threadIdx.x;
  if (e >= NE) return;
  int f = flag[0];
  int s = edge_at(edges, f, e);
  int d = edge_at(edges, f, NE + e);
  int pos = atomicAdd(&fillc[d], 1);
  int2 v;
  v.x = s;
  v.y = __float_as_int(dinv[s] * dinv[d]);
  csr[rowstart[d] + pos] = v;
}

// ---------- fp32 -> bf16 convert (8 elems/thread) ----------
__global__ void k_cvt(const float4* __restrict__ in, uint4* __restrict__ out) {
  int i = blockIdx.x * 256 + threadIdx.x;  // group of 8 elements
  float4 a = in[(size_t)i * 2], b = in[(size_t)i * 2 + 1];
  uint4 o;
  o.x = packbf(a.x, a.y); o.y = packbf(a.z, a.w);
  o.z = packbf(b.x, b.y); o.w = packbf(b.z, b.w);
  out[i] = o;
}

// ---------- gather-aggregate core (bf16 rows, fp32 accumulate) ----------
// Half-wave (32 lanes) per node; lane covers 4 channels (one uint2 = 4 bf16).
#define AGG_BODY(IN2, G, LANE, A0, A1, A2, A3)                                   \
  float dv = dinv[G];                                                            \
  float s0 = dv * dv;                                                            \
  uint2 xv = IN2[(size_t)(G)*32 + (LANE)];                                       \
  float A0 = s0 * bflo(xv.x), A1 = s0 * bfhi(xv.x);                              \
  float A2 = s0 * bflo(xv.y), A3 = s0 * bfhi(xv.y);                              \
  int i = rowstart[G], end = rowstart[(G) + 1];                                  \
  for (; i + 3 < end; i += 4) {                                                  \
    int2 e0 = csr[i], e1 = csr[i + 1], e2 = csr[i + 2], e3 = csr[i + 3];         \
    uint2 v0 = IN2[(size_t)e0.x * 32 + (LANE)];                                  \
    uint2 v1 = IN2[(size_t)e1.x * 32 + (LANE)];                                  \
    uint2 v2 = IN2[(size_t)e2.x * 32 + (LANE)];                                  \
    uint2 v3 = IN2[(size_t)e3.x * 32 + (LANE)];                                  \
    float n0 = __int_as_float(e0.y), n1 = __int_as_float(e1.y);                  \
    float n2 = __int_as_float(e2.y), n3 = __int_as_float(e3.y);                  \
    A0 = fmaf(n0, bflo(v0.x), A0); A1 = fmaf(n0, bfhi(v0.x), A1);                \
    A2 = fmaf(n0, bflo(v0.y), A2); A3 = fmaf(n0, bfhi(v0.y), A3);                \
    A0 = fmaf(n1, bflo(v1.x), A0); A1 = fmaf(n1, bfhi(v1.x), A1);                \
    A2 = fmaf(n1, bflo(v1.y), A2); A3 = fmaf(n1, bfhi(v1.y), A3);                \
    A0 = fmaf(n2, bflo(v2.x), A0); A1 = fmaf(n2, bfhi(v2.x), A1);                \
    A2 = fmaf(n2, bflo(v2.y), A2); A3 = fmaf(n2, bfhi(v2.y), A3);                \
    A0 = fmaf(n3, bflo(v3.x), A0); A1 = fmaf(n3, bfhi(v3.x), A1);                \
    A2 = fmaf(n3, bflo(v3.y), A2); A3 = fmaf(n3, bfhi(v3.y), A3);                \
  }                                                                              \
  for (; i < end; ++i) {                                                         \
    int2 e0 = csr[i];                                                            \
    float n0 = __int_as_float(e0.y);                                             \
    uint2 v0 = IN2[(size_t)e0.x * 32 + (LANE)];                                  \
    A0 = fmaf(n0, bflo(v0.x), A0); A1 = fmaf(n0, bfhi(v0.x), A1);                \
    A2 = fmaf(n0, bflo(v0.y), A2); A3 = fmaf(n0, bfhi(v0.y), A3);                \
  }

// agg1: out[v] = Agg(in)[v], bf16 out
__global__ __launch_bounds__(256) void k_agg1(const uint2* __restrict__ in2,
                                              uint2* __restrict__ out2,
                                              const int* __restrict__ rowstart,
                                              const int2* __restrict__ csr,
                                              const float* __restrict__ dinv) {
  int g = blockIdx.x * 8 + (threadIdx.x >> 5);
  int lane = threadIdx.x & 31;
  AGG_BODY(in2, g, lane, a0, a1, a2, a3)
  uint2 o;
  o.x = packbf(a0, a1);
  o.y = packbf(a2, a3);
  out2[(size_t)g * 32 + lane] = o;
}

// agg2 + fused per-graph sum pool (block of 8 nodes lies within one graph: 200%8==0)
__global__ __launch_bounds__(256) void k_agg2(const uint2* __restrict__ in2,
                                              float* __restrict__ poolsum,
                                              const int* __restrict__ rowstart,
                                              const int2* __restrict__ csr,
                                              const float* __restrict__ dinv) {
  __shared__ float sh[8][128];
  int g = blockIdx.x * 8 + (threadIdx.x >> 5);
  int lane = threadIdx.x & 31;
  AGG_BODY(in2, g, lane, a0, a1, a2, a3)
  int w = threadIdx.x >> 5;
  sh[w][lane * 4 + 0] = a0;
  sh[w][lane * 4 + 1] = a1;
  sh[w][lane * 4 + 2] = a2;
  sh[w][lane * 4 + 3] = a3;
  __syncthreads();
  int tid = threadIdx.x;
  if (tid < 128) {
    float s = 0.f;
#pragma unroll
    for (int n = 0; n < 8; ++n) s += sh[n][tid];
    atomicAdd(&poolsum[(blockIdx.x / 25) * 128 + tid], s);
  }
}

// ---------- GEMM1: bf16 A [M x 128] @ fp32 W -> bf16 out (relu) ----------
__global__ __launch_bounds__(256) void k_gemm1(const unsigned short* __restrict__ A,
                                               const float* __restrict__ W,
                                               const float* __restrict__ bias,
                                               unsigned int* __restrict__ out, int M) {
  __shared__ float Xs[32 * 132];
  __shared__ float Ws[32 * 128];
  const int tid = threadIdx.x;
  const int row0 = blockIdx.x * 128;
  const int rg = tid >> 4, cg = tid & 15;
  const int r0 = rg * 8, c0 = cg * 8;

  float bl[8];
#pragma unroll
  for (int j = 0; j < 8; ++j) bl[j] = bias[c0 + j];

  float acc[8][8];
#pragma unroll
  for (int i = 0; i < 8; ++i)
#pragma unroll
    for (int j = 0; j < 8; ++j) acc[i][j] = 0.f;

  for (int kt = 0; kt < 128; kt += 32) {
    __syncthreads();
#pragma unroll
    for (int i = tid; i < 1024; i += 256) {
      int r = i >> 3, c4 = i & 7;
      uint2 v = make_uint2(0u, 0u);
      if (row0 + r < M) v = *(const uint2*)&A[(size_t)(row0 + r) * 128 + kt + c4 * 4];
      Xs[(c4 * 4 + 0) * 132 + r] = bflo(v.x);
      Xs[(c4 * 4 + 1) * 132 + r] = bfhi(v.x);
      Xs[(c4 * 4 + 2) * 132 + r] = bflo(v.y);
      Xs[(c4 * 4 + 3) * 132 + r] = bfhi(v.y);
    }
#pragma unroll
    for (int i = tid; i < 1024; i += 256) {
      int k = i >> 5, c4 = i & 31;
      *(float4*)&Ws[k * 128 + c4 * 4] = *(const float4*)&W[(size_t)(kt + k) * 128 + c4 * 4];
    }
    __syncthreads();
#pragma unroll 8
    for (int k = 0; k < 32; ++k) {
      float4 x0 = *(const float4*)&Xs[k * 132 + r0];
      float4 x1 = *(const float4*)&Xs[k * 132 + r0 + 4];
      float4 w0 = *(const float4*)&Ws[k * 128 + c0];
      float4 w1 = *(const float4*)&Ws[k * 128 + c0 + 4];
      float xr[8] = {x0.x, x0.y, x0.z, x0.w, x1.x, x1.y, x1.z, x1.w};
      float wr[8] = {w0.x, w0.y, w0.z, w0.w, w1.x, w1.y, w1.z, w1.w};
#pragma unroll
      for (int i = 0; i < 8; ++i)
#pragma unroll
        for (int j = 0; j < 8; ++j) acc[i][j] = fmaf(xr[i], wr[j], acc[i][j]);
    }
  }

#pragma unroll
  for (int i = 0; i < 8; ++i) {
    int r = row0 + r0 + i;
    if (r < M) {
      float o[8];
#pragma unroll
      for (int j = 0; j < 8; ++j) o[j] = fmaxf(acc[i][j] + bl[j], 0.f);
      uint4 pk;
      pk.x = packbf(o[0], o[1]); pk.y = packbf(o[2], o[3]);
      pk.z = packbf(o[4], o[5]); pk.w = packbf(o[6], o[7]);
      *(uint4*)&out[(size_t)r * 64 + c0 / 2] = pk;
    }
  }
}

// ---------- GEMM2: fp32 A (scaled) @ fp32 W -> fp32 out ----------
__global__ __launch_bounds__(256) void k_gemm2(const float* __restrict__ A,
                                               const float* __restrict__ W,
                                               const float* __restrict__ bias,
                                               float* __restrict__ out, int M, float ascale) {
  __shared__ float Xs[32 * 132];
  __shared__ float Ws[32 * 128];
  const int tid = threadIdx.x;
  const int row0 = blockIdx.x * 128;
  const int rg = tid >> 4, cg = tid & 15;
  const int r0 = rg * 8, c0 = cg * 8;

  float bl[8];
#pragma unroll
  for (int j = 0; j < 8; ++j) bl[j] = bias[c0 + j];

  float acc[8][8];
#pragma unroll
  for (int i = 0; i < 8; ++i)
#pragma unroll
    for (int j = 0; j < 8; ++j) acc[i][j] = 0.f;

  for (int kt = 0; kt < 128; kt += 32) {
    __syncthreads();
#pragma unroll
    for (int i = tid; i < 1024; i += 256) {
      int r = i >> 3, c4 = i & 7;
      float4 v = make_float4(0.f, 0.f, 0.f, 0.f);
      if (row0 + r < M) v = *(const float4*)&A[(size_t)(row0 + r) * 128 + kt + c4 * 4];
      Xs[(c4 * 4 + 0) * 132 + r] = v.x * ascale;
      Xs[(c4 * 4 + 1) * 132 + r] = v.y * ascale;
      Xs[(c4 * 4 + 2) * 132 + r] = v.z * ascale;
      Xs[(c4 * 4 + 3) * 132 + r] = v.w * ascale;
    }
#pragma unroll
    for (int i = tid; i < 1024; i += 256) {
      int k = i >> 5, c4 = i & 31;
      *(float4*)&Ws[k * 128 + c4 * 4] = *(const float4*)&W[(size_t)(kt + k) * 128 + c4 * 4];
    }
    __syncthreads();
#pragma unroll 8
    for (int k = 0; k < 32; ++k) {
      float4 x0 = *(const float4*)&Xs[k * 132 + r0];
      float4 x1 = *(const float4*)&Xs[k * 132 + r0 + 4];
      float4 w0 = *(const float4*)&Ws[k * 128 + c0];
      float4 w1 = *(const float4*)&Ws[k * 128 + c0 + 4];
      float xr[8] = {x0.x, x0.y, x0.z, x0.w, x1.x, x1.y, x1.z, x1.w};
      float wr[8] = {w0.x, w0.y, w0.z, w0.w, w1.x, w1.y, w1.z, w1.w};
#pragma unroll
      for (int i = 0; i < 8; ++i)
#pragma unroll
        for (int j = 0; j < 8; ++j) acc[i][j] = fmaf(xr[i], wr[j], acc[i][j]);
    }
  }

#pragma unroll
  for (int i = 0; i < 8; ++i) {
    int r = row0 + r0 + i;
    if (r < M) {
      float o[8];
#pragma unroll
      for (int j = 0; j < 8; ++j) o[j] = acc[i][j] + bl[j];
      *(float4*)&out[(size_t)r * 128 + c0] = make_float4(o[0], o[1], o[2], o[3]);
      *(float4*)&out[(size_t)r * 128 + c0 + 4] = make_float4(o[4], o[5], o[6], o[7]);
    }
  }
}

extern "C" void kernel_launch(void* const* d_in, const int* in_sizes, int n_in,
                              void* d_out, int out_size, void* d_ws, size_t ws_size,
                              hipStream_t stream) {
  const float* x  = (const float*)d_in[0];
  const void* edges = d_in[1];
  const float* W1 = (const float*)d_in[3];
  const float* b1 = (const float*)d_in[4];
  const float* W2 = (const float*)d_in[5];
  const float* b2 = (const float*)d_in[6];
  float* out = (float*)d_out;

  // workspace layout (bytes), ~91.5 MB total
  char* ws = (char*)d_ws;
  int*   cnt      = (int*)(ws + 0);           // 400000  } zeroed
  int*   fillc    = (int*)(ws + 400000);      // 400000  } zeroed
  float* poolsum  = (float*)(ws + 800000);    // 256000  } zeroed
  int*   rowstart = (int*)(ws + 1056000);     // 400016
  int*   bsums    = (int*)(ws + 1456016);     // 2048
  float* dinv     = (float*)(ws + 1458064);   // 400000
  int*   flag     = (int*)(ws + 1858064);     // 16
  int2*  csr      = (int2*)(ws + 1858080);    // 12.8 MB
  void*  xb       = (void*)(ws + 14658080);   // 25.6 MB  bf16 x
  void*  aggb     = (void*)(ws + 40258080);   // 25.6 MB  bf16 agg1
  void*  h1b      = (void*)(ws + 65858080);   // 25.6 MB  bf16 h1

  hipMemsetAsync(ws, 0, 1056000, stream);  // cnt + fillc + poolsum

  k_detect<<<1, 64, 0, stream>>>(edges, flag);
  k_count<<<(NE + 255) / 256, 256, 0, stream>>>(edges, flag, cnt);
  k_dinv<<<(NN + 255) / 256, 256, 0, stream>>>(cnt, dinv);
  k_scan_block<<<391, 256, 0, stream>>>(cnt, rowstart, bsums);
  k_scan_sums<<<1, 512, 0, stream>>>(bsums, 391);
  k_scan_add<<<391, 256, 0, stream>>>(rowstart, bsums);
  k_fill<<<(NE + 255) / 256, 256, 0, stream>>>(edges, flag, rowstart, fillc, dinv, csr);

  // x -> bf16
  k_cvt<<<(NN * HD / 8 + 255) / 256, 256, 0, stream>>>((const float4*)x, (uint4*)xb);

  // conv1: aggb = Agg(xb); h1b = relu(aggb @ W1 + b1)
  k_agg1<<<NN / 8, 256, 0, stream>>>((const uint2*)xb, (uint2*)aggb, rowstart, csr, dinv);
  k_gemm1<<<(NN + 127) / 128, 256, 0, stream>>>((const unsigned short*)aggb, W1, b1,
                                                (unsigned int*)h1b, NN);
  // conv2 fused with pool: poolsum = sum_g(Agg(h1b)); out = (poolsum/200) @ W2 + b2
  k_agg2<<<NN / 8, 256, 0, stream>>>((const uint2*)h1b, poolsum, rowstart, csr, dinv);
  k_gemm2<<<(NG + 127) / 128, 256, 0, stream>>>(poolsum, W2, b2, out, NG, 1.f / (float)NPG);
}